// Round 1
// baseline (347.852 us; speedup 1.0000x reference)
//
#include <hip/hip_runtime.h>
#include <stdint.h>
#include <stddef.h>

#define HEADS 8
#define DH 32
#define DMODEL 256
#define LN_EPS 1e-5f

typedef unsigned short u16;
typedef __bf16 bf16x8 __attribute__((ext_vector_type(8)));
typedef unsigned short u16x8 __attribute__((ext_vector_type(8)));
typedef float f32x4 __attribute__((ext_vector_type(4)));

static __device__ __forceinline__ u16 f2bf(float f) {
    union { float f; uint32_t u; } v; v.f = f;
    return (u16)((v.u + 0x7fffu + ((v.u >> 16) & 1u)) >> 16);  // RNE
}
static __device__ __forceinline__ bf16x8 ldbf8(const u16* p) {
    return __builtin_bit_cast(bf16x8, *reinterpret_cast<const u16x8*>(p));
}

// ---------------- fp32 -> bf16 convert (row-major copy) ----------------
__global__ __launch_bounds__(256) void cvt_f32_bf16(const float* __restrict__ in,
                                                    u16* __restrict__ out, int n) {
    int i = (blockIdx.x * 256 + threadIdx.x) * 4;
    int stride = gridDim.x * 256 * 4;
    for (; i < n; i += stride) {
        float4 f = *reinterpret_cast<const float4*>(in + i);
        ushort4 o = make_ushort4(f2bf(f.x), f2bf(f.y), f2bf(f.z), f2bf(f.w));
        *reinterpret_cast<ushort4*>(out + i) = o;
    }
}

// ---------------- batched transpose + convert: W[K][N] -> Wt[N][K] bf16 ----------------
struct TDesc { const float* src; u16* dst; int K; int N; };
struct TArgs { TDesc d[10]; };

__global__ __launch_bounds__(256) void transpose_cvt(TArgs args) {
    TDesc d = args.d[blockIdx.y];
    const int ntx = d.N >> 5;
    const int tiles = (d.K >> 5) * ntx;
    if ((int)blockIdx.x >= tiles) return;
    const int tk = (blockIdx.x / ntx) << 5;
    const int tn = (blockIdx.x % ntx) << 5;
    __shared__ float t[32][33];
    const int lx = threadIdx.x & 31;
    const int ly = threadIdx.x >> 5;
#pragma unroll
    for (int i = 0; i < 4; ++i)
        t[ly + 8 * i][lx] = d.src[(size_t)(tk + ly + 8 * i) * d.N + tn + lx];
    __syncthreads();
#pragma unroll
    for (int i = 0; i < 4; ++i)
        d.dst[(size_t)(tn + ly + 8 * i) * d.K + tk + lx] = f2bf(t[lx][ly + 8 * i]);
}

// ---------------- MFMA GEMM: C[M][N] = A[M][K] @ B + bias ----------------
// A: bf16 [M][K] row-major. Bt: bf16 [N][K] (= B^T) row-major. bias: f32 [N].
// MODE 0: f32 out [M][N].  MODE 1: bf16 out [M][N].  MODE 2: bf16 out TRANSPOSED [N][M].
// Fragment layouts (mfma_f32_16x16x32_bf16):
//   A: lane l holds A[l&15][(l>>4)*8 + j]   (8 contiguous K)
//   B: lane l holds B[(l>>4)*8 + j][l&15]   = Bt[l&15][(l>>4)*8 + j]
//   D: lane l, reg r -> row=(l>>4)*4+r, col=l&15   (m89-verified)
template<int MODE, bool RELU>
__global__ __launch_bounds__(256) void gemm_bias(
    const u16* __restrict__ A, const u16* __restrict__ Bt,
    const float* __restrict__ bias, void* __restrict__ Cout,
    int M, int N, int K, int ntm)
{
    const int lane = threadIdx.x & 63;
    const int wave = threadIdx.x >> 6;
    const int l15 = lane & 15, lhi = lane >> 4;
    const int tm = (blockIdx.x % ntm) * 128;
    const int tn = (blockIdx.x / ntm) * 64;
    const int wm = tm + wave * 32;

    const f32x4 z4 = {0.f, 0.f, 0.f, 0.f};
    f32x4 acc[2][4];
#pragma unroll
    for (int i = 0; i < 2; ++i)
#pragma unroll
        for (int j = 0; j < 4; ++j) acc[i][j] = z4;

    const u16* a0p = A + (size_t)(wm + l15) * K + lhi * 8;
    const u16* a1p = a0p + (size_t)16 * K;
    const u16* b0p = Bt + (size_t)(tn + l15) * K + lhi * 8;

    for (int k = 0; k < K; k += 32) {
        bf16x8 a0 = ldbf8(a0p + k);
        bf16x8 a1 = ldbf8(a1p + k);
#pragma unroll
        for (int j = 0; j < 4; ++j) {
            bf16x8 b = ldbf8(b0p + (size_t)j * 16 * K + k);
            acc[0][j] = __builtin_amdgcn_mfma_f32_16x16x32_bf16(a0, b, acc[0][j], 0, 0, 0);
            acc[1][j] = __builtin_amdgcn_mfma_f32_16x16x32_bf16(a1, b, acc[1][j], 0, 0, 0);
        }
    }

#pragma unroll
    for (int i = 0; i < 2; ++i) {
#pragma unroll
        for (int j = 0; j < 4; ++j) {
            const int col = tn + j * 16 + l15;
            const float bv = bias[col];
            const int row0 = wm + i * 16 + lhi * 4;
            if (MODE == 0) {
                float* C = (float*)Cout;
#pragma unroll
                for (int r = 0; r < 4; ++r) {
                    float v = acc[i][j][r] + bv;
                    if (RELU) v = fmaxf(v, 0.f);
                    C[(size_t)(row0 + r) * N + col] = v;
                }
            } else if (MODE == 1) {
                u16* C = (u16*)Cout;
#pragma unroll
                for (int r = 0; r < 4; ++r) {
                    float v = acc[i][j][r] + bv;
                    if (RELU) v = fmaxf(v, 0.f);
                    C[(size_t)(row0 + r) * N + col] = f2bf(v);
                }
            } else {  // MODE 2: transposed bf16: C[col][row], rows r=0..3 contiguous
                u16* C = (u16*)Cout;
                ushort4 o = make_ushort4(f2bf(acc[i][j][0] + bv), f2bf(acc[i][j][1] + bv),
                                         f2bf(acc[i][j][2] + bv), f2bf(acc[i][j][3] + bv));
                *reinterpret_cast<ushort4*>(C + (size_t)col * M + row0) = o;
            }
        }
    }
}

// ---------------- fused flash attention ----------------
// Qb [B*Sq][256], Kb [B*Sk][256] bf16 row-major; Vt [256][MkTot] bf16 (V transposed);
// mask f32 [B][Sk]; Ob [B*Sq][256] bf16.
// Block = 4 waves; each wave owns 32 q-rows; block covers 128 q-rows of one (b,h).
__global__ __launch_bounds__(256) void attn_kernel(
    const u16* __restrict__ Qb, const u16* __restrict__ Kb,
    const u16* __restrict__ Vt, const float* __restrict__ mask,
    u16* __restrict__ Ob, int Sq, int Sk, int MkTot)
{
    const int wave = threadIdx.x >> 6;
    const int lane = threadIdx.x & 63;
    const int l15 = lane & 15, lhi = lane >> 4;
    const int nqc = Sq >> 7;
    const int bh = blockIdx.x / nqc;
    const int qc = blockIdx.x % nqc;
    const int b = bh >> 3;
    const int h = bh & 7;
    const int colh = h * DH;
    const int qrow0 = b * Sq + (qc << 7) + wave * 32;

    __shared__ __align__(16) u16 plds[4][32][72];  // +8 pad breaks bank conflicts

    const f32x4 z4 = {0.f, 0.f, 0.f, 0.f};
    bf16x8 qf[2];
#pragma unroll
    for (int i = 0; i < 2; ++i)
        qf[i] = ldbf8(Qb + (size_t)(qrow0 + i * 16 + l15) * DMODEL + colh + lhi * 8);

    f32x4 ctx[2][2];
#pragma unroll
    for (int i = 0; i < 2; ++i)
#pragma unroll
        for (int j = 0; j < 2; ++j) ctx[i][j] = z4;

    float mrow[2][4], ssum[2][4];
#pragma unroll
    for (int i = 0; i < 2; ++i)
#pragma unroll
        for (int r = 0; r < 4; ++r) { mrow[i][r] = -1e30f; ssum[i][r] = 0.f; }

    const float scale = 0.17677669529663687f;  // 1/sqrt(32)
    const float* mb = mask + (size_t)b * Sk;
    const u16* kbase = Kb + (size_t)(b * Sk) * DMODEL + colh + lhi * 8;

    for (int kt = 0; kt < Sk; kt += 64) {
        // ---- S = Q @ K^T (A=Q frags, B=K rows read K-contiguous) ----
        f32x4 s[2][4];
#pragma unroll
        for (int j = 0; j < 4; ++j) {
            bf16x8 kf = ldbf8(kbase + (size_t)(kt + j * 16 + l15) * DMODEL);
            s[0][j] = __builtin_amdgcn_mfma_f32_16x16x32_bf16(qf[0], kf, z4, 0, 0, 0);
            s[1][j] = __builtin_amdgcn_mfma_f32_16x16x32_bf16(qf[1], kf, z4, 0, 0, 0);
        }
        float mk[4];
#pragma unroll
        for (int j = 0; j < 4; ++j) mk[j] = mb[kt + j * 16 + l15];
#pragma unroll
        for (int i = 0; i < 2; ++i)
#pragma unroll
            for (int j = 0; j < 4; ++j)
#pragma unroll
                for (int r = 0; r < 4; ++r)
                    s[i][j][r] = s[i][j][r] * scale + mk[j];

        // ---- online softmax (row lives in a 16-lane group) ----
#pragma unroll
        for (int i = 0; i < 2; ++i) {
#pragma unroll
            for (int r = 0; r < 4; ++r) {
                float mx = fmaxf(fmaxf(s[i][0][r], s[i][1][r]), fmaxf(s[i][2][r], s[i][3][r]));
                mx = fmaxf(mx, __shfl_xor(mx, 1, 64));
                mx = fmaxf(mx, __shfl_xor(mx, 2, 64));
                mx = fmaxf(mx, __shfl_xor(mx, 4, 64));
                mx = fmaxf(mx, __shfl_xor(mx, 8, 64));
                float mn = fmaxf(mrow[i][r], mx);
                float corr = __expf(mrow[i][r] - mn);
                mrow[i][r] = mn;
                float ps = 0.f;
#pragma unroll
                for (int j = 0; j < 4; ++j) {
                    float p = __expf(s[i][j][r] - mn);
                    s[i][j][r] = p;
                    ps += p;
                }
                ps += __shfl_xor(ps, 1, 64);
                ps += __shfl_xor(ps, 2, 64);
                ps += __shfl_xor(ps, 4, 64);
                ps += __shfl_xor(ps, 8, 64);
                ssum[i][r] = ssum[i][r] * corr + ps;
                ctx[i][0][r] *= corr;
                ctx[i][1][r] *= corr;
            }
        }

        // ---- P (C-layout) -> LDS -> A-fragment layout ----
        asm volatile("s_waitcnt lgkmcnt(0)" ::: "memory");  // prior-iter reads drained
#pragma unroll
        for (int i = 0; i < 2; ++i)
#pragma unroll
            for (int j = 0; j < 4; ++j)
#pragma unroll
                for (int r = 0; r < 4; ++r)
                    plds[wave][i * 16 + lhi * 4 + r][j * 16 + l15] = f2bf(s[i][j][r]);
        asm volatile("s_waitcnt lgkmcnt(0)" ::: "memory");  // wave-local writes visible

        // ---- ctx += P @ V  (B-fragment from V^T, K-contiguous) ----
#pragma unroll
        for (int ks = 0; ks < 2; ++ks) {
            bf16x8 pa[2];
            pa[0] = ldbf8(&plds[wave][l15][ks * 32 + lhi * 8]);
            pa[1] = ldbf8(&plds[wave][16 + l15][ks * 32 + lhi * 8]);
#pragma unroll
            for (int n2 = 0; n2 < 2; ++n2) {
                bf16x8 vf = ldbf8(Vt + (size_t)(colh + n2 * 16 + l15) * MkTot +
                                  b * Sk + kt + ks * 32 + lhi * 8);
                ctx[0][n2] = __builtin_amdgcn_mfma_f32_16x16x32_bf16(pa[0], vf, ctx[0][n2], 0, 0, 0);
                ctx[1][n2] = __builtin_amdgcn_mfma_f32_16x16x32_bf16(pa[1], vf, ctx[1][n2], 0, 0, 0);
            }
        }
    }

    // ---- epilogue: ctx / ssum -> bf16 ----
#pragma unroll
    for (int i = 0; i < 2; ++i)
#pragma unroll
        for (int r = 0; r < 4; ++r) {
            const float inv = 1.0f / ssum[i][r];
            const int row = qrow0 + i * 16 + lhi * 4 + r;
#pragma unroll
            for (int n2 = 0; n2 < 2; ++n2)
                Ob[(size_t)row * DMODEL + colh + n2 * 16 + l15] = f2bf(ctx[i][n2][r] * inv);
        }
}

// ---------------- LayerNorm (fused residual add; optional second LN of 2*y) ----------------
// 1 wave per row (64 lanes x 4 floats = 256). Writes f32 always, bf16 optionally.
template<bool DBL, bool WBF>
__global__ __launch_bounds__(256) void ln_kernel(
    const float* __restrict__ X, const float* __restrict__ Res,
    const float* __restrict__ g1p, const float* __restrict__ b1p,
    const float* __restrict__ g2p, const float* __restrict__ b2p,
    float* __restrict__ Of, u16* __restrict__ Oh)
{
    const int lane = threadIdx.x & 63;
    const int row = blockIdx.x * 4 + (threadIdx.x >> 6);
    const size_t base = (size_t)row * DMODEL + lane * 4;
    float4 x = *reinterpret_cast<const float4*>(X + base);
    float4 rr = *reinterpret_cast<const float4*>(Res + base);
    float v[4] = {x.x + rr.x, x.y + rr.y, x.z + rr.z, x.w + rr.w};
    float s = v[0] + v[1] + v[2] + v[3];
    float q = v[0] * v[0] + v[1] * v[1] + v[2] * v[2] + v[3] * v[3];
#pragma unroll
    for (int m = 1; m < 64; m <<= 1) { s += __shfl_xor(s, m, 64); q += __shfl_xor(q, m, 64); }
    float mean = s * (1.0f / DMODEL);
    float rstd = rsqrtf(fmaxf(q * (1.0f / DMODEL) - mean * mean, 0.f) + LN_EPS);
    float4 g = *reinterpret_cast<const float4*>(g1p + lane * 4);
    float4 bb = *reinterpret_cast<const float4*>(b1p + lane * 4);
    float y[4];
    y[0] = (v[0] - mean) * rstd * g.x + bb.x;
    y[1] = (v[1] - mean) * rstd * g.y + bb.y;
    y[2] = (v[2] - mean) * rstd * g.z + bb.z;
    y[3] = (v[3] - mean) * rstd * g.w + bb.w;
    if constexpr (DBL) {  // z = LN(2*y) with g2,b2
#pragma unroll
        for (int k2 = 0; k2 < 4; ++k2) y[k2] *= 2.0f;
        float s2 = y[0] + y[1] + y[2] + y[3];
        float q2 = y[0] * y[0] + y[1] * y[1] + y[2] * y[2] + y[3] * y[3];
#pragma unroll
        for (int m = 1; m < 64; m <<= 1) { s2 += __shfl_xor(s2, m, 64); q2 += __shfl_xor(q2, m, 64); }
        float mean2 = s2 * (1.0f / DMODEL);
        float rstd2 = rsqrtf(fmaxf(q2 * (1.0f / DMODEL) - mean2 * mean2, 0.f) + LN_EPS);
        float4 g2 = *reinterpret_cast<const float4*>(g2p + lane * 4);
        float4 b2 = *reinterpret_cast<const float4*>(b2p + lane * 4);
        y[0] = (y[0] - mean2) * rstd2 * g2.x + b2.x;
        y[1] = (y[1] - mean2) * rstd2 * g2.y + b2.y;
        y[2] = (y[2] - mean2) * rstd2 * g2.z + b2.z;
        y[3] = (y[3] - mean2) * rstd2 * g2.w + b2.w;
    }
    *reinterpret_cast<float4*>(Of + base) = make_float4(y[0], y[1], y[2], y[3]);
    if constexpr (WBF) {
        ushort4 o = make_ushort4(f2bf(y[0]), f2bf(y[1]), f2bf(y[2]), f2bf(y[3]));
        *reinterpret_cast<ushort4*>(Oh + base) = o;
    }
}

// ---------------- host-side orchestration ----------------
extern "C" void kernel_launch(void* const* d_in, const int* in_sizes, int n_in,
                              void* d_out, int out_size, void* d_ws, size_t ws_size,
                              hipStream_t stream) {
    constexpr size_t MB = 1u << 20;
    if (ws_size < 70 * MB) return;  // need ~67MB scratch

    const float* vis   = (const float*)d_in[0];
    const float* txt   = (const float*)d_in[1];
    const float* vmask = (const float*)d_in[2];
    const float* tmask = (const float*)d_in[3];
    const float* sa_wq = (const float*)d_in[4];  const float* sa_bq = (const float*)d_in[5];
    const float* sa_wk = (const float*)d_in[6];  const float* sa_bk = (const float*)d_in[7];
    const float* sa_wv = (const float*)d_in[8];  const float* sa_bv = (const float*)d_in[9];
    const float* sa_wo = (const float*)d_in[10]; const float* sa_bo = (const float*)d_in[11];
    const float* ca_wq = (const float*)d_in[12]; const float* ca_bq = (const float*)d_in[13];
    const float* ca_wk = (const float*)d_in[14]; const float* ca_bk = (const float*)d_in[15];
    const float* ca_wv = (const float*)d_in[16]; const float* ca_bv = (const float*)d_in[17];
    const float* ca_wo = (const float*)d_in[18]; const float* ca_bo = (const float*)d_in[19];
    const float* ln1_g = (const float*)d_in[20]; const float* ln1_b = (const float*)d_in[21];
    const float* ln2_g = (const float*)d_in[22]; const float* ln2_b = (const float*)d_in[23];
    const float* ln3_g = (const float*)d_in[24]; const float* ln3_b = (const float*)d_in[25];
    const float* ln4_g = (const float*)d_in[26]; const float* ln4_b = (const float*)d_in[27];
    const float* fc1_w = (const float*)d_in[28]; const float* fc1_b = (const float*)d_in[29];
    const float* fc2_w = (const float*)d_in[30]; const float* fc2_b = (const float*)d_in[31];

    const int B = 4, Sq = 2048, St = 1024;
    const int Mq = B * Sq;   // 8192
    const int Mt = B * St;   // 4096

    char* ws = (char*)d_ws;
    u16*   Xv_bf   = (u16*)(ws + 0);         // 4MB
    u16*   Xt_bf   = (u16*)(ws + 4 * MB);    // 2MB
    u16*   q_bf    = (u16*)(ws + 6 * MB);    // 4MB
    u16*   k_bf    = (u16*)(ws + 10 * MB);   // 4MB (CA uses 2MB)
    u16*   vt_bf   = (u16*)(ws + 14 * MB);   // 4MB transposed V
    u16*   ctx_bf  = (u16*)(ws + 18 * MB);   // 4MB
    u16*   ffn1_bf = (u16*)(ws + 0);         // 32MB, overlaps the above (dead by FFN)
    float* attn_f  = (float*)(ws + 32 * MB); // 8MB
    float* h1_f    = (float*)(ws + 40 * MB); // 8MB
    u16*   h1_bf   = (u16*)(ws + 48 * MB);   // 4MB
    float* h3_f    = (float*)(ws + 52 * MB); // 8MB
    u16*   h3_bf   = (u16*)(ws + 60 * MB);   // 4MB
    u16*   wts     = (u16*)(ws + 64 * MB);   // 3MB transposed weights
    float* ffn2_f  = attn_f;                  // reuse (attn_f dead after LN2/3)

    u16* wq_t  = wts + 0 * 65536;
    u16* wk_t  = wts + 1 * 65536;
    u16* wv_t  = wts + 2 * 65536;
    u16* wo_t  = wts + 3 * 65536;
    u16* cwq_t = wts + 4 * 65536;
    u16* cwk_t = wts + 5 * 65536;
    u16* cwv_t = wts + 6 * 65536;
    u16* cwo_t = wts + 7 * 65536;
    u16* fc1_t = wts + 8 * 65536;            // [2048][256]
    u16* fc2_t = fc1_t + 2048 * 256;         // [256][2048]

    // 1) input conversions
    cvt_f32_bf16<<<2048, 256, 0, stream>>>(vis, Xv_bf, Mq * DMODEL);
    cvt_f32_bf16<<<1024, 256, 0, stream>>>(txt, Xt_bf, Mt * DMODEL);

    // 2) weight transposes (batched)
    TArgs ta;
    ta.d[0] = {sa_wq, wq_t, 256, 256};  ta.d[1] = {sa_wk, wk_t, 256, 256};
    ta.d[2] = {sa_wv, wv_t, 256, 256};  ta.d[3] = {sa_wo, wo_t, 256, 256};
    ta.d[4] = {ca_wq, cwq_t, 256, 256}; ta.d[5] = {ca_wk, cwk_t, 256, 256};
    ta.d[6] = {ca_wv, cwv_t, 256, 256}; ta.d[7] = {ca_wo, cwo_t, 256, 256};
    ta.d[8] = {fc1_w, fc1_t, 256, 2048};
    ta.d[9] = {fc2_w, fc2_t, 2048, 256};
    transpose_cvt<<<dim3(512, 10), 256, 0, stream>>>(ta);

    auto gemm_grid = [](int M, int N) { return dim3((M / 128) * (N / 64)); };

    // 3) self-attention
    gemm_bias<1, false><<<gemm_grid(Mq, 256), 256, 0, stream>>>(Xv_bf, wq_t, sa_bq, q_bf,  Mq, 256, 256, Mq / 128);
    gemm_bias<1, false><<<gemm_grid(Mq, 256), 256, 0, stream>>>(Xv_bf, wk_t, sa_bk, k_bf,  Mq, 256, 256, Mq / 128);
    gemm_bias<2, false><<<gemm_grid(Mq, 256), 256, 0, stream>>>(Xv_bf, wv_t, sa_bv, vt_bf, Mq, 256, 256, Mq / 128);
    attn_kernel<<<dim3(B * HEADS * (Sq / 128)), 256, 0, stream>>>(q_bf, k_bf, vt_bf, vmask, ctx_bf, Sq, Sq, Mq);
    gemm_bias<0, false><<<gemm_grid(Mq, 256), 256, 0, stream>>>(ctx_bf, wo_t, sa_bo, attn_f, Mq, 256, 256, Mq / 128);
    ln_kernel<false, true><<<dim3(Mq / 4), 256, 0, stream>>>(attn_f, vis, ln1_g, ln1_b, nullptr, nullptr, h1_f, h1_bf);

    // 4) cross-attention
    gemm_bias<1, false><<<gemm_grid(Mq, 256), 256, 0, stream>>>(h1_bf, cwq_t, ca_bq, q_bf,  Mq, 256, 256, Mq / 128);
    gemm_bias<1, false><<<gemm_grid(Mt, 256), 256, 0, stream>>>(Xt_bf, cwk_t, ca_bk, k_bf,  Mt, 256, 256, Mt / 128);
    gemm_bias<2, false><<<gemm_grid(Mt, 256), 256, 0, stream>>>(Xt_bf, cwv_t, ca_bv, vt_bf, Mt, 256, 256, Mt / 128);
    attn_kernel<<<dim3(B * HEADS * (Sq / 128)), 256, 0, stream>>>(q_bf, k_bf, vt_bf, tmask, ctx_bf, Sq, St, Mt);
    gemm_bias<0, false><<<gemm_grid(Mq, 256), 256, 0, stream>>>(ctx_bf, cwo_t, ca_bo, attn_f, Mq, 256, 256, Mq / 128);
    // LN2 then LN3(2*y), fused
    ln_kernel<true, true><<<dim3(Mq / 4), 256, 0, stream>>>(attn_f, h1_f, ln2_g, ln2_b, ln3_g, ln3_b, h3_f, h3_bf);

    // 5) FFN
    gemm_bias<1, true><<<gemm_grid(Mq, 2048), 256, 0, stream>>>(h3_bf, fc1_t, fc1_b, ffn1_bf, Mq, 2048, 256, Mq / 128);
    gemm_bias<0, false><<<gemm_grid(Mq, 256), 256, 0, stream>>>(ffn1_bf, fc2_t, fc2_b, ffn2_f, Mq, 256, 2048, Mq / 128);
    ln_kernel<false, false><<<dim3(Mq / 4), 256, 0, stream>>>(ffn2_f, h3_f, ln4_g, ln4_b, nullptr, nullptr, (float*)d_out, nullptr);
}